// Round 1
// baseline (903.682 us; speedup 1.0000x reference)
//
#include <hip/hip_runtime.h>
#include <hip/hip_bf16.h>
#include <stdint.h>
#include <math.h>

typedef __attribute__((ext_vector_type(4))) float f32x4;
typedef __attribute__((ext_vector_type(8))) short s16x8;

typedef const __attribute__((address_space(1))) void* gas_ptr;
typedef __attribute__((address_space(3))) void* las_ptr;

__device__ __forceinline__ float bf2f(unsigned short u) {
    union { unsigned int i; float f; } x; x.i = ((unsigned int)u) << 16; return x.f;
}
__device__ __forceinline__ unsigned short f2bf(float f) {
    union { float f; unsigned int u; } x; x.f = f;
    unsigned int r = x.u + 0x7FFFu + ((x.u >> 16) & 1u);
    return (unsigned short)(r >> 16);
}

// ---------------- fp32 -> bf16 ----------------
__global__ __launch_bounds__(256) void cvt_f32_bf16(const float* __restrict__ src,
                                                    unsigned short* __restrict__ dst,
                                                    long n) {
    long i = ((long)blockIdx.x * 256 + threadIdx.x) * 8;
    if (i + 8 > n) return;
    f32x4 a = *(const f32x4*)(src + i);
    f32x4 b = *(const f32x4*)(src + i + 4);
    s16x8 o;
    o[0] = (short)f2bf(a[0]); o[1] = (short)f2bf(a[1]);
    o[2] = (short)f2bf(a[2]); o[3] = (short)f2bf(a[3]);
    o[4] = (short)f2bf(b[0]); o[5] = (short)f2bf(b[1]);
    o[6] = (short)f2bf(b[2]); o[7] = (short)f2bf(b[3]);
    *(s16x8*)(dst + i) = o;
}

// ---------------- bf16 GEMM: C = alpha * A[M,K] @ B[N,K]^T ----------------
// m97 structure: 128x128 tile, BK=32, 4 waves (2x2), each wave 64x64 = 4x4
// fragments of 16x16x32, global_load_lds width=16, single-buffer 2-barrier loop.
#define BM 128
#define BN 128
#define BK 32

template <typename CT>
__global__ __launch_bounds__(256)
void gemm_bt(const unsigned short* __restrict__ A,
             const unsigned short* __restrict__ B,
             CT* __restrict__ C,
             int M, int N, int K,
             long sA, long sB, long sC, float alpha)
{
    A += (long)blockIdx.z * sA;
    B += (long)blockIdx.z * sB;
    C += (long)blockIdx.z * sC;

    __shared__ unsigned short As[BM * BK];
    __shared__ unsigned short Bs[BN * BK];

    const int t    = threadIdx.x;
    const int lane = t & 63;
    const int wid  = t >> 6;
    const int wr   = (wid >> 1) * 64;   // wave row offset in tile
    const int wc   = (wid & 1) * 64;    // wave col offset in tile
    const int brow = blockIdx.x * BM;
    const int bcol = blockIdx.y * BN;

    // staging: thread t loads 8 bf16 (16B); two passes cover 128x32 tile
    const int soff = t * 8;             // element offset in LDS (linear)
    const int srow = t >> 2;            // 0..63
    const int scol = (t & 3) * 8;

    const int lr = lane & 15;
    const int lk = (lane >> 4) * 8;

    f32x4 acc[4][4];
    #pragma unroll
    for (int m = 0; m < 4; ++m)
        #pragma unroll
        for (int n = 0; n < 4; ++n)
            acc[m][n] = {0.f, 0.f, 0.f, 0.f};

    const unsigned short* Abase = A + (long)(brow + srow) * K + scol;
    const unsigned short* Bbase = B + (long)(bcol + srow) * K + scol;
    const long half = 64L * K;

    for (int k0 = 0; k0 < K; k0 += BK) {
        __builtin_amdgcn_global_load_lds((gas_ptr)(Abase + k0),        (las_ptr)(As + soff),        16, 0, 0);
        __builtin_amdgcn_global_load_lds((gas_ptr)(Abase + half + k0), (las_ptr)(As + soff + 2048), 16, 0, 0);
        __builtin_amdgcn_global_load_lds((gas_ptr)(Bbase + k0),        (las_ptr)(Bs + soff),        16, 0, 0);
        __builtin_amdgcn_global_load_lds((gas_ptr)(Bbase + half + k0), (las_ptr)(Bs + soff + 2048), 16, 0, 0);
        __syncthreads();   // drains vmcnt before barrier

        s16x8 af[4], bfr[4];
        #pragma unroll
        for (int m = 0; m < 4; ++m)
            af[m] = *(const s16x8*)(As + (wr + m * 16 + lr) * BK + lk);
        #pragma unroll
        for (int n = 0; n < 4; ++n)
            bfr[n] = *(const s16x8*)(Bs + (wc + n * 16 + lr) * BK + lk);
        #pragma unroll
        for (int m = 0; m < 4; ++m)
            #pragma unroll
            for (int n = 0; n < 4; ++n)
                acc[m][n] = __builtin_amdgcn_mfma_f32_16x16x32_bf16(af[m], bfr[n], acc[m][n], 0, 0, 0);
        __syncthreads();
    }

    // C/D layout: col = lane&15, row = (lane>>4)*4 + i  [guide m89/m91 verified]
    const int lq = (lane >> 4) * 4;
    #pragma unroll
    for (int m = 0; m < 4; ++m) {
        #pragma unroll
        for (int n = 0; n < 4; ++n) {
            #pragma unroll
            for (int i = 0; i < 4; ++i) {
                long row = brow + wr + m * 16 + lq + i;
                long col = bcol + wc + n * 16 + lr;
                float vv = acc[m][n][i] * alpha;
                if constexpr (sizeof(CT) == 2) {
                    ((unsigned short*)C)[row * (long)N + col] = f2bf(vv);
                } else {
                    ((float*)C)[row * (long)N + col] = vv;
                }
            }
        }
    }
}

// ---------------- bf16 transpose: dst[c][r] = src[r][c], per-batch ----------------
__global__ __launch_bounds__(256) void transpose_bf16(const unsigned short* __restrict__ src,
                                                      unsigned short* __restrict__ dst,
                                                      int srows, int scols) {
    __shared__ unsigned short tile[64][66];
    const long bofs = (long)blockIdx.z * srows * scols;
    const unsigned short* s = src + bofs;
    unsigned short* d = dst + bofs;
    const int c0 = blockIdx.x * 64;
    const int r0 = blockIdx.y * 64;
    const int tx = threadIdx.x & 15;
    const int ty = threadIdx.x >> 4;

    #pragma unroll
    for (int k = 0; k < 4; ++k) {
        int r = ty + 16 * k;
        ushort4 v = *(const ushort4*)(s + (long)(r0 + r) * scols + c0 + tx * 4);
        tile[r][tx * 4 + 0] = v.x; tile[r][tx * 4 + 1] = v.y;
        tile[r][tx * 4 + 2] = v.z; tile[r][tx * 4 + 3] = v.w;
    }
    __syncthreads();
    #pragma unroll
    for (int k = 0; k < 4; ++k) {
        int dr = ty + 16 * k;   // dst row within tile = source col
        ushort4 v;
        v.x = tile[tx * 4 + 0][dr]; v.y = tile[tx * 4 + 1][dr];
        v.z = tile[tx * 4 + 2][dr]; v.w = tile[tx * 4 + 3][dr];
        *(ushort4*)(d + (long)(c0 + dr) * srows + r0 + tx * 4) = v;
    }
}

// ---------------- row softmax, in place, bf16, ncols = 4096 ----------------
__global__ __launch_bounds__(256) void softmax_inplace(unsigned short* __restrict__ S, int ncols) {
    const long row = blockIdx.x;
    unsigned short* p = S + row * (long)ncols;
    const int t = threadIdx.x;
    const int wid = t >> 6;

    ushort4 raw[4];
    const ushort4* pv = (const ushort4*)(p + t * 16);
    #pragma unroll
    for (int i = 0; i < 4; ++i) raw[i] = pv[i];

    float v[16];
    float mx = -1e30f;
    #pragma unroll
    for (int i = 0; i < 4; ++i) {
        v[4*i+0] = bf2f(raw[i].x); v[4*i+1] = bf2f(raw[i].y);
        v[4*i+2] = bf2f(raw[i].z); v[4*i+3] = bf2f(raw[i].w);
    }
    #pragma unroll
    for (int i = 0; i < 16; ++i) mx = fmaxf(mx, v[i]);
    #pragma unroll
    for (int off = 32; off > 0; off >>= 1) mx = fmaxf(mx, __shfl_xor(mx, off));

    __shared__ float red[8];
    if ((t & 63) == 0) red[wid] = mx;
    __syncthreads();
    mx = fmaxf(fmaxf(red[0], red[1]), fmaxf(red[2], red[3]));

    float sum = 0.f;
    #pragma unroll
    for (int i = 0; i < 16; ++i) { v[i] = __expf(v[i] - mx); sum += v[i]; }
    #pragma unroll
    for (int off = 32; off > 0; off >>= 1) sum += __shfl_xor(sum, off);
    __syncthreads();
    if ((t & 63) == 0) red[4 + wid] = sum;
    __syncthreads();
    sum = red[4] + red[5] + red[6] + red[7];
    const float inv = 1.0f / sum;

    ushort4* po = (ushort4*)(p + t * 16);
    #pragma unroll
    for (int i = 0; i < 4; ++i) {
        ushort4 o;
        o.x = f2bf(v[4*i+0] * inv); o.y = f2bf(v[4*i+1] * inv);
        o.z = f2bf(v[4*i+2] * inv); o.w = f2bf(v[4*i+3] * inv);
        po[i] = o;
    }
}

extern "C" void kernel_launch(void* const* d_in, const int* in_sizes, int n_in,
                              void* d_out, int out_size, void* d_ws, size_t ws_size,
                              hipStream_t stream) {
    const float* x  = (const float*)d_in[0];
    const float* wq = (const float*)d_in[1];
    const float* wk = (const float*)d_in[2];
    const float* wv = (const float*)d_in[3];
    const float* wo = (const float*)d_in[4];
    float* out = (float*)d_out;

    const long SDIM = 2048, SEQ = 4096, BATCH = 2;
    const long MS = BATCH * SEQ;       // 8192
    const long XN = MS * SDIM;         // 16,777,216
    const long WN = SDIM * SDIM;       // 4,194,304

    unsigned short* ws  = (unsigned short*)d_ws;
    unsigned short* Xbf = ws;               // XN elems (reused as Vt later)
    unsigned short* Wqb = ws + XN;
    unsigned short* Wkb = Wqb + WN;
    unsigned short* Wvb = Wkb + WN;
    unsigned short* Wob = Wvb + WN;
    unsigned short* Qb  = Wob + WN;         // XN (reused as Ctx later)
    unsigned short* Kb  = Qb + XN;
    unsigned short* Vb  = Kb + XN;
    unsigned short* Sb  = Vb + XN;          // 2*4096*4096 bf16
    unsigned short* Vt  = Xbf;
    unsigned short* Ctx = Qb;

    // fp32 -> bf16 conversions
    cvt_f32_bf16<<<(int)(XN / 2048), 256, 0, stream>>>(x,  Xbf, XN);
    cvt_f32_bf16<<<(int)(WN / 2048), 256, 0, stream>>>(wq, Wqb, WN);
    cvt_f32_bf16<<<(int)(WN / 2048), 256, 0, stream>>>(wk, Wkb, WN);
    cvt_f32_bf16<<<(int)(WN / 2048), 256, 0, stream>>>(wv, Wvb, WN);
    cvt_f32_bf16<<<(int)(WN / 2048), 256, 0, stream>>>(wo, Wob, WN);

    // projections: [8192,2048] = Xbf @ W^T
    dim3 gp((unsigned)(MS / BM), (unsigned)(SDIM / BN), 1);
    gemm_bt<unsigned short><<<gp, 256, 0, stream>>>(Xbf, Wqb, Qb, (int)MS, (int)SDIM, (int)SDIM, 0, 0, 0, 1.0f);
    gemm_bt<unsigned short><<<gp, 256, 0, stream>>>(Xbf, Wkb, Kb, (int)MS, (int)SDIM, (int)SDIM, 0, 0, 0, 1.0f);
    gemm_bt<unsigned short><<<gp, 256, 0, stream>>>(Xbf, Wvb, Vb, (int)MS, (int)SDIM, (int)SDIM, 0, 0, 0, 1.0f);

    // V -> V^T per batch (Vt overwrites Xbf region; X no longer needed)
    dim3 gt((unsigned)(SDIM / 64), (unsigned)(SEQ / 64), (unsigned)BATCH);
    transpose_bf16<<<gt, 256, 0, stream>>>(Vb, Vt, (int)SEQ, (int)SDIM);

    // scores: S[b] = Q[b] @ K[b]^T * (1/sqrt(D))
    const float scale = 1.0f / sqrtf((float)SDIM);
    dim3 gs((unsigned)(SEQ / BM), (unsigned)(SEQ / BN), (unsigned)BATCH);
    gemm_bt<unsigned short><<<gs, 256, 0, stream>>>(Qb, Kb, Sb, (int)SEQ, (int)SEQ, (int)SDIM,
                                                    SEQ * SDIM, SEQ * SDIM, SEQ * SEQ, scale);

    // softmax rows in place
    softmax_inplace<<<(int)(BATCH * SEQ), 256, 0, stream>>>(Sb, (int)SEQ);

    // ctx[b] = P[b] @ Vt[b]^T : M=SEQ, N=SDIM, K=SEQ  (Ctx overwrites Qb)
    dim3 gc((unsigned)(SEQ / BM), (unsigned)(SDIM / BN), (unsigned)BATCH);
    gemm_bt<unsigned short><<<gc, 256, 0, stream>>>(Sb, Vt, Ctx, (int)SEQ, (int)SDIM, (int)SEQ,
                                                    SEQ * SEQ, SDIM * SEQ, SEQ * SDIM, 1.0f);

    // out = Ctx @ Wo^T  (fp32 out, flat [8192,2048])
    gemm_bt<float><<<gp, 256, 0, stream>>>(Ctx, Wob, out, (int)MS, (int)SDIM, (int)SDIM, 0, 0, 0, 1.0f);
}

// Round 2
// 640.820 us; speedup vs baseline: 1.4102x; 1.4102x over previous
//
#include <hip/hip_runtime.h>
#include <hip/hip_bf16.h>
#include <stdint.h>
#include <math.h>

typedef __attribute__((ext_vector_type(4))) float f32x4;
typedef __attribute__((ext_vector_type(8))) short s16x8;

typedef const __attribute__((address_space(1))) void* gas_ptr;
typedef __attribute__((address_space(3))) void* las_ptr;

__device__ __forceinline__ float bf2f(unsigned short u) {
    union { unsigned int i; float f; } x; x.i = ((unsigned int)u) << 16; return x.f;
}
__device__ __forceinline__ unsigned short f2bf(float f) {
    union { float f; unsigned int u; } x; x.f = f;
    unsigned int r = x.u + 0x7FFFu + ((x.u >> 16) & 1u);
    return (unsigned short)(r >> 16);
}

// ---------------- fp32 -> bf16 ----------------
__global__ __launch_bounds__(256) void cvt_f32_bf16(const float* __restrict__ src,
                                                    unsigned short* __restrict__ dst,
                                                    long n) {
    long i = ((long)blockIdx.x * 256 + threadIdx.x) * 8;
    if (i + 8 > n) return;
    f32x4 a = *(const f32x4*)(src + i);
    f32x4 b = *(const f32x4*)(src + i + 4);
    s16x8 o;
    o[0] = (short)f2bf(a[0]); o[1] = (short)f2bf(a[1]);
    o[2] = (short)f2bf(a[2]); o[3] = (short)f2bf(a[3]);
    o[4] = (short)f2bf(b[0]); o[5] = (short)f2bf(b[1]);
    o[6] = (short)f2bf(b[2]); o[7] = (short)f2bf(b[3]);
    *(s16x8*)(dst + i) = o;
}

// ============ 256x256 8-phase bf16 GEMM: C = alpha * A[M,K] @ B[N,K]^T ============
// 512 threads = 8 waves (2 wave-rows x 4 wave-cols), wave tile 128x64.
// LDS [buf][A|B][sub][128][64]: A split by qm (rows {0-63,128-191} vs rest),
// B split by qn (rows 0-31 mod 64 vs 32-63 mod 64). Phases p=(qm,qn) in order
// (0,0),(0,1),(1,0),(1,1). Stage schedule (tile t): p0->t+1.A1, p1->t+1.B1,
// p2->t+2.A0, p3->t+2.B0. Boundary: vmcnt(4) (t+2's 4 loads in flight).
// Swizzle: element col ^= ((row&7)<<3), applied on pre-swizzled global source
// (linear global_load_lds dest) and on ds_read address (rule 21).
template <typename CT>
__global__ __launch_bounds__(512, 2)
void gemm256_bt(const unsigned short* __restrict__ A,
                const unsigned short* __restrict__ B,
                CT* __restrict__ C,
                int N, int K, int nt,
                long sA, long sB, long sC, float alpha)
{
    A += (long)blockIdx.z * sA;
    B += (long)blockIdx.z * sB;
    C += (long)blockIdx.z * sC;

    __shared__ unsigned short L[2][2][2][128][64];   // 128 KiB

    const int t    = threadIdx.x;
    const int lane = t & 63;
    const int wid  = t >> 6;        // 0..7
    const int wm   = wid >> 2;      // 0..1
    const int wn   = wid & 3;       // 0..3
    const long brow = (long)blockIdx.x * 256;
    const long bcol = (long)blockIdx.y * 256;

    const int lr = lane & 15;
    const int hi = lane >> 4;            // 0..3
    const int sw = (lr & 7) << 3;        // ds_read swizzle (element units)

    // ---- staging precompute: thread t, chunk j handles linear u = t + 512j ----
    int voff[2];                 // LDS element offset u*8
    const unsigned short* pA[2][2];   // [sub][j] global src (swizzled), k0=0
    const unsigned short* pB[2][2];
    {
        const unsigned short* Ab = A + brow * K;
        const unsigned short* Bb = B + bcol * K;
        #pragma unroll
        for (int j = 0; j < 2; ++j) {
            int u  = t + 512 * j;
            int ix = u >> 3;                       // phys row in [128][64] region
            int cg = u & 7;
            int cs = (cg * 8) ^ ((ix & 7) << 3);   // pre-swizzled col
            voff[j] = u * 8;
            long ra0 = ((long)(ix >> 6) << 7) | (0 << 6) | (ix & 63);
            long ra1 = ((long)(ix >> 6) << 7) | (1 << 6) | (ix & 63);
            long rb0 = ((long)(ix >> 5) << 6) | (0 << 5) | (ix & 31);
            long rb1 = ((long)(ix >> 5) << 6) | (1 << 5) | (ix & 31);
            pA[0][j] = Ab + ra0 * K + cs;
            pA[1][j] = Ab + ra1 * K + cs;
            pB[0][j] = Bb + rb0 * K + cs;
            pB[1][j] = Bb + rb1 * K + cs;
        }
    }

#define STAGE_A(H, KT) do { \
    _Pragma("unroll") \
    for (int j = 0; j < 2; ++j) \
        __builtin_amdgcn_global_load_lds((gas_ptr)(pA[H][j] + (long)(KT) * 64), \
            (las_ptr)(&L[(KT) & 1][0][H][0][0] + voff[j]), 16, 0, 0); \
} while (0)
#define STAGE_B(H, KT) do { \
    _Pragma("unroll") \
    for (int j = 0; j < 2; ++j) \
        __builtin_amdgcn_global_load_lds((gas_ptr)(pB[H][j] + (long)(KT) * 64), \
            (las_ptr)(&L[(KT) & 1][1][H][0][0] + voff[j]), 16, 0, 0); \
} while (0)

    f32x4 acc[8][4];
    #pragma unroll
    for (int m = 0; m < 8; ++m)
        #pragma unroll
        for (int n = 0; n < 4; ++n)
            acc[m][n] = {0.f, 0.f, 0.f, 0.f};

    // ---- prologue: tile0 all 4 halves, tile1 A0+B0; wait tile0 landed ----
    STAGE_A(0, 0); STAGE_A(1, 0); STAGE_B(0, 0); STAGE_B(1, 0);
    if (nt > 1) {
        STAGE_A(0, 1); STAGE_B(0, 1);
        asm volatile("s_waitcnt vmcnt(4)" ::: "memory");
    } else {
        asm volatile("s_waitcnt vmcnt(0)" ::: "memory");
    }
    __builtin_amdgcn_s_barrier();

    for (int kt = 0; kt < nt; ++kt) {
        const int cur = kt & 1;
        #pragma unroll
        for (int p = 0; p < 4; ++p) {
            const int qm = p >> 1, qn = p & 1;
            // 12 x ds_read_b128 (swizzled)
            s16x8 af[4][2], bq[2][2];
            #pragma unroll
            for (int m = 0; m < 4; ++m)
                #pragma unroll
                for (int kk = 0; kk < 2; ++kk)
                    af[m][kk] = *(const s16x8*)&L[cur][0][qm][wm * 64 + m * 16 + lr][(kk * 32 + hi * 8) ^ sw];
            #pragma unroll
            for (int n = 0; n < 2; ++n)
                #pragma unroll
                for (int kk = 0; kk < 2; ++kk)
                    bq[n][kk] = *(const s16x8*)&L[cur][1][qn][wn * 32 + n * 16 + lr][(kk * 32 + hi * 8) ^ sw];
            // stage one half-tile (2 x global_load_lds)
            if (p == 0)      { if (kt + 1 < nt) STAGE_A(1, kt + 1); }
            else if (p == 1) { if (kt + 1 < nt) STAGE_B(1, kt + 1); }
            else if (p == 2) { if (kt + 2 < nt) STAGE_A(0, kt + 2); }
            else             { if (kt + 2 < nt) STAGE_B(0, kt + 2); }
            asm volatile("s_waitcnt lgkmcnt(8)" ::: "memory");
            __builtin_amdgcn_s_barrier();
            asm volatile("s_waitcnt lgkmcnt(0)" ::: "memory");
            __builtin_amdgcn_s_setprio(1);
            #pragma unroll
            for (int m = 0; m < 4; ++m)
                #pragma unroll
                for (int n = 0; n < 2; ++n)
                    #pragma unroll
                    for (int kk = 0; kk < 2; ++kk)
                        acc[qm * 4 + m][qn * 2 + n] = __builtin_amdgcn_mfma_f32_16x16x32_bf16(
                            af[m][kk], bq[n][kk], acc[qm * 4 + m][qn * 2 + n], 0, 0, 0);
            __builtin_amdgcn_s_setprio(0);
            if (p < 3) __builtin_amdgcn_s_barrier();
        }
        // tile boundary: ensure tile kt+1 fully landed; keep t+2's loads in flight
        if (kt + 1 < nt) {
            if (kt + 2 < nt) asm volatile("s_waitcnt vmcnt(4)" ::: "memory");
            else             asm volatile("s_waitcnt vmcnt(0)" ::: "memory");
            __builtin_amdgcn_s_barrier();
        }
    }
#undef STAGE_A
#undef STAGE_B

    // ---- epilogue: C[row][col], row = 16*am + hi*4 + i, col = 16*an + lr ----
    #pragma unroll
    for (int m = 0; m < 8; ++m) {
        #pragma unroll
        for (int n = 0; n < 4; ++n) {
            #pragma unroll
            for (int i = 0; i < 4; ++i) {
                long row = brow + wm * 128 + m * 16 + hi * 4 + i;
                long col = bcol + wn * 64 + n * 16 + lr;
                float vv = acc[m][n][i] * alpha;
                if constexpr (sizeof(CT) == 2) {
                    ((unsigned short*)C)[row * (long)N + col] = f2bf(vv);
                } else {
                    ((float*)C)[row * (long)N + col] = vv;
                }
            }
        }
    }
}

// ---------------- bf16 transpose: dst[c][r] = src[r][c], per-batch ----------------
__global__ __launch_bounds__(256) void transpose_bf16(const unsigned short* __restrict__ src,
                                                      unsigned short* __restrict__ dst,
                                                      int srows, int scols) {
    __shared__ unsigned short tile[64][66];
    const long bofs = (long)blockIdx.z * srows * scols;
    const unsigned short* s = src + bofs;
    unsigned short* d = dst + bofs;
    const int c0 = blockIdx.x * 64;
    const int r0 = blockIdx.y * 64;
    const int tx = threadIdx.x & 15;
    const int ty = threadIdx.x >> 4;

    #pragma unroll
    for (int k = 0; k < 4; ++k) {
        int r = ty + 16 * k;
        ushort4 v = *(const ushort4*)(s + (long)(r0 + r) * scols + c0 + tx * 4);
        tile[r][tx * 4 + 0] = v.x; tile[r][tx * 4 + 1] = v.y;
        tile[r][tx * 4 + 2] = v.z; tile[r][tx * 4 + 3] = v.w;
    }
    __syncthreads();
    #pragma unroll
    for (int k = 0; k < 4; ++k) {
        int dr = ty + 16 * k;
        ushort4 v;
        v.x = tile[tx * 4 + 0][dr]; v.y = tile[tx * 4 + 1][dr];
        v.z = tile[tx * 4 + 2][dr]; v.w = tile[tx * 4 + 3][dr];
        *(ushort4*)(d + (long)(c0 + dr) * srows + r0 + tx * 4) = v;
    }
}

// ---------------- row softmax, in place, bf16, ncols = 4096 ----------------
__global__ __launch_bounds__(256) void softmax_inplace(unsigned short* __restrict__ S, int ncols) {
    const long row = blockIdx.x;
    unsigned short* p = S + row * (long)ncols;
    const int t = threadIdx.x;
    const int wid = t >> 6;

    ushort4 raw[4];
    const ushort4* pv = (const ushort4*)(p + t * 16);
    #pragma unroll
    for (int i = 0; i < 4; ++i) raw[i] = pv[i];

    float v[16];
    float mx = -1e30f;
    #pragma unroll
    for (int i = 0; i < 4; ++i) {
        v[4*i+0] = bf2f(raw[i].x); v[4*i+1] = bf2f(raw[i].y);
        v[4*i+2] = bf2f(raw[i].z); v[4*i+3] = bf2f(raw[i].w);
    }
    #pragma unroll
    for (int i = 0; i < 16; ++i) mx = fmaxf(mx, v[i]);
    #pragma unroll
    for (int off = 32; off > 0; off >>= 1) mx = fmaxf(mx, __shfl_xor(mx, off));

    __shared__ float red[8];
    if ((t & 63) == 0) red[wid] = mx;
    __syncthreads();
    mx = fmaxf(fmaxf(red[0], red[1]), fmaxf(red[2], red[3]));

    float sum = 0.f;
    #pragma unroll
    for (int i = 0; i < 16; ++i) { v[i] = __expf(v[i] - mx); sum += v[i]; }
    #pragma unroll
    for (int off = 32; off > 0; off >>= 1) sum += __shfl_xor(sum, off);
    __syncthreads();
    if ((t & 63) == 0) red[4 + wid] = sum;
    __syncthreads();
    sum = red[4] + red[5] + red[6] + red[7];
    const float inv = 1.0f / sum;

    ushort4* po = (ushort4*)(p + t * 16);
    #pragma unroll
    for (int i = 0; i < 4; ++i) {
        ushort4 o;
        o.x = f2bf(v[4*i+0] * inv); o.y = f2bf(v[4*i+1] * inv);
        o.z = f2bf(v[4*i+2] * inv); o.w = f2bf(v[4*i+3] * inv);
        po[i] = o;
    }
}

extern "C" void kernel_launch(void* const* d_in, const int* in_sizes, int n_in,
                              void* d_out, int out_size, void* d_ws, size_t ws_size,
                              hipStream_t stream) {
    const float* x  = (const float*)d_in[0];
    const float* wq = (const float*)d_in[1];
    const float* wk = (const float*)d_in[2];
    const float* wv = (const float*)d_in[3];
    const float* wo = (const float*)d_in[4];
    float* out = (float*)d_out;

    const long SDIM = 2048, SEQ = 4096, BATCH = 2;
    const long MS = BATCH * SEQ;       // 8192
    const long XN = MS * SDIM;         // 16,777,216
    const long WN = SDIM * SDIM;       // 4,194,304

    unsigned short* ws  = (unsigned short*)d_ws;
    unsigned short* Xbf = ws;               // XN elems (reused as Vt later)
    unsigned short* Wqb = ws + XN;
    unsigned short* Wkb = Wqb + WN;
    unsigned short* Wvb = Wkb + WN;
    unsigned short* Wob = Wvb + WN;
    unsigned short* Qb  = Wob + WN;         // XN (reused as Ctx later)
    unsigned short* Kb  = Qb + XN;
    unsigned short* Vb  = Kb + XN;
    unsigned short* Sb  = Vb + XN;          // 2*4096*4096 bf16
    unsigned short* Vt  = Xbf;
    unsigned short* Ctx = Qb;

    // fp32 -> bf16 conversions
    cvt_f32_bf16<<<(int)(XN / 2048), 256, 0, stream>>>(x,  Xbf, XN);
    cvt_f32_bf16<<<(int)(WN / 2048), 256, 0, stream>>>(wq, Wqb, WN);
    cvt_f32_bf16<<<(int)(WN / 2048), 256, 0, stream>>>(wk, Wkb, WN);
    cvt_f32_bf16<<<(int)(WN / 2048), 256, 0, stream>>>(wv, Wvb, WN);
    cvt_f32_bf16<<<(int)(WN / 2048), 256, 0, stream>>>(wo, Wob, WN);

    // projections: [8192,2048] = Xbf @ W^T
    dim3 gp((unsigned)(MS / 256), (unsigned)(SDIM / 256), 1);
    gemm256_bt<unsigned short><<<gp, 512, 0, stream>>>(Xbf, Wqb, Qb, (int)SDIM, (int)SDIM, (int)(SDIM / 64), 0, 0, 0, 1.0f);
    gemm256_bt<unsigned short><<<gp, 512, 0, stream>>>(Xbf, Wkb, Kb, (int)SDIM, (int)SDIM, (int)(SDIM / 64), 0, 0, 0, 1.0f);
    gemm256_bt<unsigned short><<<gp, 512, 0, stream>>>(Xbf, Wvb, Vb, (int)SDIM, (int)SDIM, (int)(SDIM / 64), 0, 0, 0, 1.0f);

    // V -> V^T per batch (Vt overwrites Xbf region; X no longer needed)
    dim3 gt((unsigned)(SDIM / 64), (unsigned)(SEQ / 64), (unsigned)BATCH);
    transpose_bf16<<<gt, 256, 0, stream>>>(Vb, Vt, (int)SEQ, (int)SDIM);

    // scores: S[b] = Q[b] @ K[b]^T * (1/sqrt(D))
    const float scale = 1.0f / sqrtf((float)SDIM);
    dim3 gs((unsigned)(SEQ / 256), (unsigned)(SEQ / 256), (unsigned)BATCH);
    gemm256_bt<unsigned short><<<gs, 512, 0, stream>>>(Qb, Kb, Sb, (int)SEQ, (int)SDIM, (int)(SDIM / 64),
                                                       SEQ * SDIM, SEQ * SDIM, SEQ * SEQ, scale);

    // softmax rows in place
    softmax_inplace<<<(int)(BATCH * SEQ), 256, 0, stream>>>(Sb, (int)SEQ);

    // ctx[b] = P[b] @ Vt[b]^T : M=SEQ, N=SDIM, K=SEQ  (Ctx overwrites Qb)
    dim3 gc((unsigned)(SEQ / 256), (unsigned)(SDIM / 256), (unsigned)BATCH);
    gemm256_bt<unsigned short><<<gc, 512, 0, stream>>>(Sb, Vt, Ctx, (int)SDIM, (int)SEQ, (int)(SEQ / 64),
                                                       SEQ * SEQ, SDIM * SEQ, SEQ * SDIM, 1.0f);

    // out = Ctx @ Wo^T  (fp32 out, flat [8192,2048])
    gemm256_bt<float><<<gp, 512, 0, stream>>>(Ctx, Wob, out, (int)SDIM, (int)SDIM, (int)(SDIM / 64), 0, 0, 0, 1.0f);
}

// Round 3
// 583.337 us; speedup vs baseline: 1.5492x; 1.0985x over previous
//
#include <hip/hip_runtime.h>
#include <hip/hip_bf16.h>
#include <stdint.h>
#include <math.h>

typedef __attribute__((ext_vector_type(4))) float f32x4;
typedef __attribute__((ext_vector_type(8))) short s16x8;

typedef const __attribute__((address_space(1))) void* gas_ptr;
typedef __attribute__((address_space(3))) void* las_ptr;

__device__ __forceinline__ float bf2f(unsigned short u) {
    union { unsigned int i; float f; } x; x.i = ((unsigned int)u) << 16; return x.f;
}
__device__ __forceinline__ unsigned short f2bf(float f) {
    union { float f; unsigned int u; } x; x.f = f;
    unsigned int r = x.u + 0x7FFFu + ((x.u >> 16) & 1u);
    return (unsigned short)(r >> 16);
}

// ---------------- fp32 -> bf16 ----------------
__global__ __launch_bounds__(256) void cvt_f32_bf16(const float* __restrict__ src,
                                                    unsigned short* __restrict__ dst,
                                                    long n) {
    long i = ((long)blockIdx.x * 256 + threadIdx.x) * 8;
    if (i + 8 > n) return;
    f32x4 a = *(const f32x4*)(src + i);
    f32x4 b = *(const f32x4*)(src + i + 4);
    s16x8 o;
    o[0] = (short)f2bf(a[0]); o[1] = (short)f2bf(a[1]);
    o[2] = (short)f2bf(a[2]); o[3] = (short)f2bf(a[3]);
    o[4] = (short)f2bf(b[0]); o[5] = (short)f2bf(b[1]);
    o[6] = (short)f2bf(b[2]); o[7] = (short)f2bf(b[3]);
    *(s16x8*)(dst + i) = o;
}

// ============ 256x256 8-phase bf16 GEMM: C = alpha * A[M,K] @ B[N,K]^T ============
// 512 threads = 8 waves (2x4), wave tile 128x64. LDS [buf][A|B][sub][128][64].
// Phase order (qm,qn): (0,0) -> (0,1) -> (1,1) -> (1,0) with REGISTER REUSE:
//   P0 reads A0(8)+B0(4), P1 reads B1(4), P2 reads A1(8), P3 reads nothing.
// 24 ds_read_b128 per K-tile per wave (minimum) vs 48 in the naive per-phase
// reload -> LDS pipe (2048 cyc/K-tile incl. staging writes) < MFMA (2483 cyc).
// Stage schedule per tile t: P0->t+1.A1, P1->t+1.B1, P2->t+2.A0, P3->t+2.B0;
// boundary vmcnt(4) keeps t+2's 4 loads in flight (T4: never drain to 0).
// Swizzle (T2): element col ^= ((row&7)<<3); pre-swizzled global source for the
// linear global_load_lds dest + same XOR on ds_read address (rule 21).
template <typename CT>
__global__ __launch_bounds__(512, 2)
void gemm256_bt(const unsigned short* __restrict__ A,
                const unsigned short* __restrict__ B,
                CT* __restrict__ C,
                int N, int K, int nt,
                long sA, long sB, long sC, float alpha)
{
    A += (long)blockIdx.z * sA;
    B += (long)blockIdx.z * sB;
    C += (long)blockIdx.z * sC;

    __shared__ unsigned short L[2][2][2][128][64];   // 128 KiB

    const int t    = threadIdx.x;
    const int lane = t & 63;
    const int wid  = t >> 6;        // 0..7
    const int wm   = wid >> 2;      // 0..1
    const int wn   = wid & 3;       // 0..3
    const long brow = (long)blockIdx.x * 256;
    const long bcol = (long)blockIdx.y * 256;

    const int lr = lane & 15;
    const int hi = lane >> 4;            // 0..3
    const int sw = (lr & 7) << 3;        // ds_read swizzle (element units)

    // ---- staging precompute: thread t, chunk j handles linear u = t + 512j ----
    int voff[2];                      // LDS element offset u*8
    const unsigned short* pA[2][2];   // [sub][j] global src (pre-swizzled), k0=0
    const unsigned short* pB[2][2];
    {
        const unsigned short* Ab = A + brow * K;
        const unsigned short* Bb = B + bcol * K;
        #pragma unroll
        for (int j = 0; j < 2; ++j) {
            int u  = t + 512 * j;
            int ix = u >> 3;                       // phys row in [128][64] region
            int cg = u & 7;
            int cs = (cg * 8) ^ ((ix & 7) << 3);   // pre-swizzled col
            voff[j] = u * 8;
            long ra0 = ((long)(ix >> 6) << 7) | (0 << 6) | (ix & 63);
            long ra1 = ((long)(ix >> 6) << 7) | (1 << 6) | (ix & 63);
            long rb0 = ((long)(ix >> 5) << 6) | (0 << 5) | (ix & 31);
            long rb1 = ((long)(ix >> 5) << 6) | (1 << 5) | (ix & 31);
            pA[0][j] = Ab + ra0 * K + cs;
            pA[1][j] = Ab + ra1 * K + cs;
            pB[0][j] = Bb + rb0 * K + cs;
            pB[1][j] = Bb + rb1 * K + cs;
        }
    }

#define STAGE_A(H, KT) do { \
    _Pragma("unroll") \
    for (int j = 0; j < 2; ++j) \
        __builtin_amdgcn_global_load_lds((gas_ptr)(pA[H][j] + (long)(KT) * 64), \
            (las_ptr)(&L[(KT) & 1][0][H][0][0] + voff[j]), 16, 0, 0); \
} while (0)
#define STAGE_B(H, KT) do { \
    _Pragma("unroll") \
    for (int j = 0; j < 2; ++j) \
        __builtin_amdgcn_global_load_lds((gas_ptr)(pB[H][j] + (long)(KT) * 64), \
            (las_ptr)(&L[(KT) & 1][1][H][0][0] + voff[j]), 16, 0, 0); \
} while (0)

#define LOAD_AF(QM) do { \
    _Pragma("unroll") \
    for (int m = 0; m < 4; ++m) \
        _Pragma("unroll") \
        for (int kk = 0; kk < 2; ++kk) \
            af[m][kk] = *(const s16x8*)&L[cur][0][QM][wm * 64 + m * 16 + lr][(kk * 32 + hi * 8) ^ sw]; \
} while (0)
#define LOAD_BQ(DST, QN) do { \
    _Pragma("unroll") \
    for (int n = 0; n < 2; ++n) \
        _Pragma("unroll") \
        for (int kk = 0; kk < 2; ++kk) \
            DST[n][kk] = *(const s16x8*)&L[cur][1][QN][wn * 32 + n * 16 + lr][(kk * 32 + hi * 8) ^ sw]; \
} while (0)
#define MFMA_Q(QM, QN, BQ) do { \
    __builtin_amdgcn_s_setprio(1); \
    _Pragma("unroll") \
    for (int m = 0; m < 4; ++m) \
        _Pragma("unroll") \
        for (int n = 0; n < 2; ++n) \
            _Pragma("unroll") \
            for (int kk = 0; kk < 2; ++kk) \
                acc[(QM) * 4 + m][(QN) * 2 + n] = __builtin_amdgcn_mfma_f32_16x16x32_bf16( \
                    af[m][kk], BQ[n][kk], acc[(QM) * 4 + m][(QN) * 2 + n], 0, 0, 0); \
    __builtin_amdgcn_s_setprio(0); \
} while (0)

    f32x4 acc[8][4];
    #pragma unroll
    for (int m = 0; m < 8; ++m)
        #pragma unroll
        for (int n = 0; n < 4; ++n)
            acc[m][n] = {0.f, 0.f, 0.f, 0.f};

    // ---- prologue: tile0 all 4 halves, tile1 A0+B0; wait tile0 landed ----
    STAGE_A(0, 0); STAGE_A(1, 0); STAGE_B(0, 0); STAGE_B(1, 0);
    if (nt > 1) {
        STAGE_A(0, 1); STAGE_B(0, 1);
        asm volatile("s_waitcnt vmcnt(4)" ::: "memory");
    } else {
        asm volatile("s_waitcnt vmcnt(0)" ::: "memory");
    }
    __builtin_amdgcn_s_barrier();

    for (int kt = 0; kt < nt; ++kt) {
        const int cur = kt & 1;
        s16x8 af[4][2], bq0[2][2], bq1[2][2];

        // ---- P0: read A0 + B0 (12), stage t+1.A1, MFMA (0,0) ----
        LOAD_AF(0);
        LOAD_BQ(bq0, 0);
        if (kt + 1 < nt) STAGE_A(1, kt + 1);
        asm volatile("s_waitcnt lgkmcnt(8)" ::: "memory");
        __builtin_amdgcn_s_barrier();
        asm volatile("s_waitcnt lgkmcnt(0)" ::: "memory");
        MFMA_Q(0, 0, bq0);
        __builtin_amdgcn_s_barrier();

        // ---- P1: read B1 (4), stage t+1.B1, MFMA (0,1) [af reused] ----
        LOAD_BQ(bq1, 1);
        if (kt + 1 < nt) STAGE_B(1, kt + 1);
        __builtin_amdgcn_s_barrier();
        asm volatile("s_waitcnt lgkmcnt(0)" ::: "memory");
        MFMA_Q(0, 1, bq1);
        __builtin_amdgcn_s_barrier();

        // ---- P2: read A1 (8), stage t+2.A0, MFMA (1,1) [bq1 reused] ----
        LOAD_AF(1);
        if (kt + 2 < nt) STAGE_A(0, kt + 2);
        asm volatile("s_waitcnt lgkmcnt(4)" ::: "memory");
        __builtin_amdgcn_s_barrier();
        asm volatile("s_waitcnt lgkmcnt(0)" ::: "memory");
        MFMA_Q(1, 1, bq1);
        __builtin_amdgcn_s_barrier();

        // ---- P3: no reads, stage t+2.B0, MFMA (1,0) [af + bq0 reused] ----
        if (kt + 2 < nt) STAGE_B(0, kt + 2);
        __builtin_amdgcn_s_barrier();
        MFMA_Q(1, 0, bq0);

        // tile boundary: tile kt+1 fully landed; keep t+2's 4 loads in flight
        if (kt + 1 < nt) {
            if (kt + 2 < nt) asm volatile("s_waitcnt vmcnt(4)" ::: "memory");
            else             asm volatile("s_waitcnt vmcnt(0)" ::: "memory");
            __builtin_amdgcn_s_barrier();
        }
    }
#undef STAGE_A
#undef STAGE_B
#undef LOAD_AF
#undef LOAD_BQ
#undef MFMA_Q

    // ---- epilogue: C[row][col], row = 16*am + hi*4 + i, col = 16*an + lr ----
    #pragma unroll
    for (int m = 0; m < 8; ++m) {
        #pragma unroll
        for (int n = 0; n < 4; ++n) {
            #pragma unroll
            for (int i = 0; i < 4; ++i) {
                long row = brow + wm * 128 + m * 16 + hi * 4 + i;
                long col = bcol + wn * 64 + n * 16 + lr;
                float vv = acc[m][n][i] * alpha;
                if constexpr (sizeof(CT) == 2) {
                    ((unsigned short*)C)[row * (long)N + col] = f2bf(vv);
                } else {
                    ((float*)C)[row * (long)N + col] = vv;
                }
            }
        }
    }
}

// ---------------- bf16 transpose: dst[c][r] = src[r][c], per-batch ----------------
__global__ __launch_bounds__(256) void transpose_bf16(const unsigned short* __restrict__ src,
                                                      unsigned short* __restrict__ dst,
                                                      int srows, int scols) {
    __shared__ unsigned short tile[64][66];
    const long bofs = (long)blockIdx.z * srows * scols;
    const unsigned short* s = src + bofs;
    unsigned short* d = dst + bofs;
    const int c0 = blockIdx.x * 64;
    const int r0 = blockIdx.y * 64;
    const int tx = threadIdx.x & 15;
    const int ty = threadIdx.x >> 4;

    #pragma unroll
    for (int k = 0; k < 4; ++k) {
        int r = ty + 16 * k;
        ushort4 v = *(const ushort4*)(s + (long)(r0 + r) * scols + c0 + tx * 4);
        tile[r][tx * 4 + 0] = v.x; tile[r][tx * 4 + 1] = v.y;
        tile[r][tx * 4 + 2] = v.z; tile[r][tx * 4 + 3] = v.w;
    }
    __syncthreads();
    #pragma unroll
    for (int k = 0; k < 4; ++k) {
        int dr = ty + 16 * k;
        ushort4 v;
        v.x = tile[tx * 4 + 0][dr]; v.y = tile[tx * 4 + 1][dr];
        v.z = tile[tx * 4 + 2][dr]; v.w = tile[tx * 4 + 3][dr];
        *(ushort4*)(d + (long)(c0 + dr) * srows + r0 + tx * 4) = v;
    }
}

// ---------------- row softmax, in place, bf16, ncols = 4096 ----------------
__global__ __launch_bounds__(256) void softmax_inplace(unsigned short* __restrict__ S, int ncols) {
    const long row = blockIdx.x;
    unsigned short* p = S + row * (long)ncols;
    const int t = threadIdx.x;
    const int wid = t >> 6;

    ushort4 raw[4];
    const ushort4* pv = (const ushort4*)(p + t * 16);
    #pragma unroll
    for (int i = 0; i < 4; ++i) raw[i] = pv[i];

    float v[16];
    float mx = -1e30f;
    #pragma unroll
    for (int i = 0; i < 4; ++i) {
        v[4*i+0] = bf2f(raw[i].x); v[4*i+1] = bf2f(raw[i].y);
        v[4*i+2] = bf2f(raw[i].z); v[4*i+3] = bf2f(raw[i].w);
    }
    #pragma unroll
    for (int i = 0; i < 16; ++i) mx = fmaxf(mx, v[i]);
    #pragma unroll
    for (int off = 32; off > 0; off >>= 1) mx = fmaxf(mx, __shfl_xor(mx, off));

    __shared__ float red[8];
    if ((t & 63) == 0) red[wid] = mx;
    __syncthreads();
    mx = fmaxf(fmaxf(red[0], red[1]), fmaxf(red[2], red[3]));

    float sum = 0.f;
    #pragma unroll
    for (int i = 0; i < 16; ++i) { v[i] = __expf(v[i] - mx); sum += v[i]; }
    #pragma unroll
    for (int off = 32; off > 0; off >>= 1) sum += __shfl_xor(sum, off);
    __syncthreads();
    if ((t & 63) == 0) red[4 + wid] = sum;
    __syncthreads();
    sum = red[4] + red[5] + red[6] + red[7];
    const float inv = 1.0f / sum;

    ushort4* po = (ushort4*)(p + t * 16);
    #pragma unroll
    for (int i = 0; i < 4; ++i) {
        ushort4 o;
        o.x = f2bf(v[4*i+0] * inv); o.y = f2bf(v[4*i+1] * inv);
        o.z = f2bf(v[4*i+2] * inv); o.w = f2bf(v[4*i+3] * inv);
        po[i] = o;
    }
}

extern "C" void kernel_launch(void* const* d_in, const int* in_sizes, int n_in,
                              void* d_out, int out_size, void* d_ws, size_t ws_size,
                              hipStream_t stream) {
    const float* x  = (const float*)d_in[0];
    const float* wq = (const float*)d_in[1];
    const float* wk = (const float*)d_in[2];
    const float* wv = (const float*)d_in[3];
    const float* wo = (const float*)d_in[4];
    float* out = (float*)d_out;

    const long SDIM = 2048, SEQ = 4096, BATCH = 2;
    const long MS = BATCH * SEQ;       // 8192
    const long XN = MS * SDIM;         // 16,777,216
    const long WN = SDIM * SDIM;       // 4,194,304

    unsigned short* ws  = (unsigned short*)d_ws;
    unsigned short* Xbf = ws;               // XN elems (reused as Vt later)
    unsigned short* Wqb = ws + XN;
    unsigned short* Wkb = Wqb + WN;
    unsigned short* Wvb = Wkb + WN;
    unsigned short* Wob = Wvb + WN;
    unsigned short* Qb  = Wob + WN;         // XN (reused as Ctx later)
    unsigned short* Kb  = Qb + XN;
    unsigned short* Vb  = Kb + XN;
    unsigned short* Sb  = Vb + XN;          // 2*4096*4096 bf16
    unsigned short* Vt  = Xbf;
    unsigned short* Ctx = Qb;

    // fp32 -> bf16 conversions
    cvt_f32_bf16<<<(int)(XN / 2048), 256, 0, stream>>>(x,  Xbf, XN);
    cvt_f32_bf16<<<(int)(WN / 2048), 256, 0, stream>>>(wq, Wqb, WN);
    cvt_f32_bf16<<<(int)(WN / 2048), 256, 0, stream>>>(wk, Wkb, WN);
    cvt_f32_bf16<<<(int)(WN / 2048), 256, 0, stream>>>(wv, Wvb, WN);
    cvt_f32_bf16<<<(int)(WN / 2048), 256, 0, stream>>>(wo, Wob, WN);

    // projections: [8192,2048] = Xbf @ W^T
    dim3 gp((unsigned)(MS / 256), (unsigned)(SDIM / 256), 1);
    gemm256_bt<unsigned short><<<gp, 512, 0, stream>>>(Xbf, Wqb, Qb, (int)SDIM, (int)SDIM, (int)(SDIM / 64), 0, 0, 0, 1.0f);
    gemm256_bt<unsigned short><<<gp, 512, 0, stream>>>(Xbf, Wkb, Kb, (int)SDIM, (int)SDIM, (int)(SDIM / 64), 0, 0, 0, 1.0f);
    gemm256_bt<unsigned short><<<gp, 512, 0, stream>>>(Xbf, Wvb, Vb, (int)SDIM, (int)SDIM, (int)(SDIM / 64), 0, 0, 0, 1.0f);

    // V -> V^T per batch (Vt overwrites Xbf region; X no longer needed)
    dim3 gt((unsigned)(SDIM / 64), (unsigned)(SEQ / 64), (unsigned)BATCH);
    transpose_bf16<<<gt, 256, 0, stream>>>(Vb, Vt, (int)SEQ, (int)SDIM);

    // scores: S[b] = Q[b] @ K[b]^T * (1/sqrt(D))
    const float scale = 1.0f / sqrtf((float)SDIM);
    dim3 gs((unsigned)(SEQ / 256), (unsigned)(SEQ / 256), (unsigned)BATCH);
    gemm256_bt<unsigned short><<<gs, 512, 0, stream>>>(Qb, Kb, Sb, (int)SEQ, (int)SDIM, (int)(SDIM / 64),
                                                       SEQ * SDIM, SEQ * SDIM, SEQ * SEQ, scale);

    // softmax rows in place
    softmax_inplace<<<(int)(BATCH * SEQ), 256, 0, stream>>>(Sb, (int)SEQ);

    // ctx[b] = P[b] @ Vt[b]^T : M=SEQ, N=SDIM, K=SEQ  (Ctx overwrites Qb)
    dim3 gc((unsigned)(SEQ / 256), (unsigned)(SDIM / 256), (unsigned)BATCH);
    gemm256_bt<unsigned short><<<gc, 512, 0, stream>>>(Sb, Vt, Ctx, (int)SDIM, (int)SEQ, (int)(SEQ / 64),
                                                       SEQ * SEQ, SDIM * SEQ, SEQ * SDIM, 1.0f);

    // out = Ctx @ Wo^T  (fp32 out, flat [8192,2048])
    gemm256_bt<float><<<gp, 512, 0, stream>>>(Ctx, Wob, out, (int)SDIM, (int)SDIM, (int)(SDIM / 64), 0, 0, 0, 1.0f);
}